// Round 5
// baseline (1087.178 us; speedup 1.0000x reference)
//
#include <hip/hip_runtime.h>

// AttnBlock2D: GroupNorm -> fused QKV 1x1conv -> 1-head attention (hw=4096, dh=512) -> proj + residual
// b=8, c=512, h=w=64. bf16 MFMA (16x16x32), f32 accumulate.
// R5: fixes R4 ws overflow (PV back inside slice loop, S-slice buffer reused; adaptive G 4->2->1).
//     Keeps: named gemm wrappers for rocprof, BK=32 high-occupancy gemm_res, XCD swizzle,
//     both-sides LDS XOR swizzle, dbuf 2-phase K-loop.

#define BATCH 8
#define CCH 512
#define HWP 4096
#define NG 32

typedef __attribute__((ext_vector_type(8))) short s16x8;
typedef __attribute__((ext_vector_type(4))) float f32x4;

__device__ __forceinline__ unsigned short f2bf(float f) {
  union { float f; unsigned u; } v; v.f = f;
  return (unsigned short)((v.u + 0x7FFFu + ((v.u >> 16) & 1u)) >> 16);
}
__device__ __forceinline__ float bf2f(unsigned short h) {
  union { unsigned u; float f; } v; v.u = ((unsigned)h) << 16;
  return v.f;
}

// ---------------- weight convert f32 -> bf16 (4 matrices) + qkv bias concat ----------------
__global__ void cvt_w(const float* __restrict__ w0, const float* __restrict__ w1,
                      const float* __restrict__ w2, const float* __restrict__ w3,
                      const float* __restrict__ bq, const float* __restrict__ bk,
                      const float* __restrict__ bv,
                      unsigned short* __restrict__ out, float* __restrict__ bcat) {
  int i = blockIdx.x * 256 + threadIdx.x;
  const int n = CCH * CCH;
  if (i < CCH) {
    bcat[i]           = bq[i];
    bcat[CCH + i]     = bk[i];
    bcat[2 * CCH + i] = bv[i];
  }
  if (i < n) {
    out[i]         = f2bf(w0[i]);
    out[n + i]     = f2bf(w1[i]);
    out[2 * n + i] = f2bf(w2[i]);
    out[3 * n + i] = f2bf(w3[i]);
  }
}

// ---------------- GroupNorm stats: one block per (b,g) ----------------
__global__ void gn_stats(const float* __restrict__ x, float* __restrict__ stats) {
  const int bg = blockIdx.x;                     // b*32+g ; group data contiguous 16*4096 f32
  const float* base = x + (size_t)bg * (16 * HWP);
  float s = 0.f, sq = 0.f;
  for (int i = threadIdx.x; i < 16 * HWP / 4; i += 256) {
    float4 v = ((const float4*)base)[i];
    s += v.x + v.y + v.z + v.w;
    sq += v.x * v.x + v.y * v.y + v.z * v.z + v.w * v.w;
  }
  #pragma unroll
  for (int o = 32; o; o >>= 1) { s += __shfl_xor(s, o); sq += __shfl_xor(sq, o); }
  __shared__ float ls[4], lq[4];
  const int wv = threadIdx.x >> 6;
  if ((threadIdx.x & 63) == 0) { ls[wv] = s; lq[wv] = sq; }
  __syncthreads();
  if (threadIdx.x == 0) {
    s = ls[0] + ls[1] + ls[2] + ls[3];
    sq = lq[0] + lq[1] + lq[2] + lq[3];
    const float inv_n = 1.f / (16.f * HWP);
    float mean = s * inv_n;
    float var = sq * inv_n - mean * mean;
    stats[2 * bg] = mean;
    stats[2 * bg + 1] = rsqrtf(var + 1e-5f);
  }
}

// ---------------- GroupNorm apply + transpose -> h_t (hw, c) bf16 ----------------
__global__ void gn_apply(const float* __restrict__ x, const float* __restrict__ stats,
                         const float* __restrict__ scale, const float* __restrict__ bias,
                         unsigned short* __restrict__ ht) {
  // grid (HWP/64, CCH/64, B), block 256
  const int p0 = blockIdx.x * 64, c0 = blockIdx.y * 64, b = blockIdx.z;
  const int tx = threadIdx.x & 63, ty = threadIdx.x >> 6;
  __shared__ unsigned short tile[64][65];
  #pragma unroll 4
  for (int j = 0; j < 16; ++j) {
    int cl = ty + j * 4;
    int c = c0 + cl;
    int g = c >> 4;
    float mean = stats[(b * NG + g) * 2];
    float rstd = stats[(b * NG + g) * 2 + 1];
    float v = x[((size_t)(b * CCH + c)) * HWP + p0 + tx];
    v = (v - mean) * rstd * scale[c] + bias[c];
    tile[cl][tx] = f2bf(v);
  }
  __syncthreads();
  #pragma unroll 4
  for (int j = 0; j < 16; ++j) {
    int pl = ty + j * 4;
    ht[((size_t)b * HWP + p0 + pl) * CCH + c0 + tx] = tile[tx][pl];
  }
}

// ---------------- V transpose: qkv (b, p, 1536)[cols 1024:1536) -> vT (b, c, p) ----------------
__global__ void transpose_v(const unsigned short* __restrict__ qkv,
                            unsigned short* __restrict__ vT) {
  const int p0 = blockIdx.x * 64, c0 = blockIdx.y * 64, b = blockIdx.z;
  const int tx = threadIdx.x & 63, ty = threadIdx.x >> 6;
  __shared__ unsigned short tile[64][65];
  #pragma unroll 4
  for (int j = 0; j < 16; ++j) {
    int pl = ty + j * 4;
    tile[pl][tx] = qkv[((size_t)b * HWP + p0 + pl) * 1536 + 1024 + c0 + tx];
  }
  __syncthreads();
  #pragma unroll 4
  for (int j = 0; j < 16; ++j) {
    int cl = ty + j * 4;
    vT[((size_t)b * CCH + c0 + cl) * HWP + p0 + tx] = tile[tx][cl];
  }
}

// ---------------- NT GEMM body: C[.,.] = scale * A[M,K] * B[N,K]^T (+biases, +residual) ----------------
// 128x128 tile, 4 waves, 16x16x32 MFMA. Double-buffered LDS (2*2*BK*128*2 B); pre-swizzled
// global_load_lds staging + XOR-swizzled ds_read (both-sides). Bijective XCD swizzle.
// MODE 0: bf16 out. MODE 1: f32 out, coalesced LDS-bounce epilogue with residual.
template<int BK, int MODE>
__device__ __forceinline__ void gemm_body(
    const unsigned short* __restrict__ A, const unsigned short* __restrict__ Bm,
    void* __restrict__ Cm, const float* __restrict__ biasRow,
    const float* __restrict__ biasCol, const float* __restrict__ Res,
    int K, int lda, int ldb, int ldc, float scale,
    long long sA, long long sB, long long sC, long long sRes) {
  constexpr int CPR = BK / 8;            // 16B chunks per row
  constexpr int NIT = (128 * CPR) / 256; // stage iters per tensor (4 or 2)
  // --- bijective XCD swizzle ---
  const int nbx = gridDim.x, nby = gridDim.y;
  const int nb = nbx * nby * gridDim.z;
  int lin = (blockIdx.z * nby + blockIdx.y) * nbx + blockIdx.x;
  int bx, by, bz;
  if ((nb & 7) == 0) {
    int logical = (lin & 7) * (nb >> 3) + (lin >> 3);
    bx = logical % nbx;
    int t = logical / nbx;
    by = t % nby;
    bz = t / nby;
  } else { bx = blockIdx.x; by = blockIdx.y; bz = blockIdx.z; }

  const unsigned short* Ab = A + (size_t)bz * sA;
  const unsigned short* Bb = Bm + (size_t)bz * sB;
  const int m0 = by * 128, n0 = bx * 128;
  __shared__ __align__(16) unsigned short sm[2][2][128 * BK];  // [A/B][dbuf][tile]
  const int tid = threadIdx.x, wave = tid >> 6, lane = tid & 63;
  const int wr = (wave >> 1) * 64, wc = (wave & 1) * 64;
  const int lr = lane & 15, lkc = lane >> 4;
  f32x4 acc[4][4] = {};

  const int chunkBase = wave * 64 + lane;             // 0..255
  int srow[NIT], sc8[NIT];
  #pragma unroll
  for (int it = 0; it < NIT; ++it) {
    int chunk = it * 256 + chunkBase;
    int row = chunk / CPR, cc = chunk % CPR;
    int f = (BK == 32) ? ((row ^ (row >> 2)) & 3) : (row & 7);
    srow[it] = row;
    sc8[it] = (cc ^ f) * 8;
  }

  #define STAGE(buf, kt)                                                                 \
    {                                                                                    \
      _Pragma("unroll")                                                                  \
      for (int it = 0; it < NIT; ++it) {                                                 \
        __builtin_amdgcn_global_load_lds(                                                \
            (const __attribute__((address_space(1))) unsigned int*)(Ab + (size_t)(m0 + srow[it]) * lda + (kt) + sc8[it]), \
            (__attribute__((address_space(3))) unsigned int*)(&sm[0][buf][0] + (size_t)(it * 256 + wave * 64) * 8),       \
            16, 0, 0);                                                                   \
        __builtin_amdgcn_global_load_lds(                                                \
            (const __attribute__((address_space(1))) unsigned int*)(Bb + (size_t)(n0 + srow[it]) * ldb + (kt) + sc8[it]), \
            (__attribute__((address_space(3))) unsigned int*)(&sm[1][buf][0] + (size_t)(it * 256 + wave * 64) * 8),       \
            16, 0, 0);                                                                   \
      }                                                                                  \
    }

  STAGE(0, 0);
  __syncthreads();
  int cur = 0;
  for (int kt = 0; kt < K; kt += BK) {
    if (kt + BK < K) STAGE(cur ^ 1, kt + BK);
    #pragma unroll
    for (int kk = 0; kk < BK; kk += 32) {
      const int jbase = (kk >> 3) + lkc;
      s16x8 af[4], bfv[4];
      #pragma unroll
      for (int m = 0; m < 4; ++m) {
        int r = wr + m * 16 + lr;
        int f = (BK == 32) ? ((r ^ (r >> 2)) & 3) : (r & 7);
        af[m] = *(const s16x8*)&sm[0][cur][r * BK + ((jbase ^ f) << 3)];
      }
      #pragma unroll
      for (int n = 0; n < 4; ++n) {
        int r = wc + n * 16 + lr;
        int f = (BK == 32) ? ((r ^ (r >> 2)) & 3) : (r & 7);
        bfv[n] = *(const s16x8*)&sm[1][cur][r * BK + ((jbase ^ f) << 3)];
      }
      #pragma unroll
      for (int m = 0; m < 4; ++m)
        #pragma unroll
        for (int n = 0; n < 4; ++n)
          acc[m][n] = __builtin_amdgcn_mfma_f32_16x16x32_bf16(af[m], bfv[n], acc[m][n], 0, 0, 0);
    }
    __syncthreads();
    cur ^= 1;
  }
  #undef STAGE

  const int r0 = (lane >> 4) * 4;
  if (MODE == 0) {
    const int ccol = lane & 15;
    #pragma unroll
    for (int m = 0; m < 4; ++m) {
      const int gm = m0 + wr + m * 16 + r0;
      #pragma unroll
      for (int n = 0; n < 4; ++n) {
        const int gn = n0 + wc + n * 16 + ccol;
        float bc = biasCol ? biasCol[gn] : 0.f;
        #pragma unroll
        for (int r = 0; r < 4; ++r) {
          const int grow = gm + r;
          float val = acc[m][n][r] * scale + bc;
          if (biasRow) val += biasRow[grow];
          size_t idx = (size_t)grow * ldc + gn;
          ((unsigned short*)Cm)[(size_t)bz * sC + idx] = f2bf(val);
        }
      }
    }
  } else {
    // f32 out: LDS bounce in NP passes of PR rows, float4 residual+store
    constexpr int PR = (BK == 64) ? 64 : 32;
    constexpr int NP = 128 / PR;
    constexpr int IT = PR * 128 / 1024;   // float4 store iters per pass
    float* ft = (float*)&sm[0][0][0];
    float* Cf = (float*)Cm;
    #pragma unroll
    for (int pass = 0; pass < NP; ++pass) {
      const int prow0 = pass * PR;
      __syncthreads();
      if (wr <= prow0 && prow0 < wr + 64) {
        const int mlo = (prow0 - wr) >> 4;
        #pragma unroll
        for (int mi = 0; mi < PR / 16; ++mi) {
          const int m = mlo + mi;
          const int rl0 = mi * 16 + r0;
          #pragma unroll
          for (int n = 0; n < 4; ++n) {
            const int cl = wc + n * 16 + (lane & 15);
            float bc = biasCol ? biasCol[n0 + cl] : 0.f;
            #pragma unroll
            for (int r = 0; r < 4; ++r) {
              float val = acc[m][n][r] * scale + bc;
              if (biasRow) val += biasRow[m0 + prow0 + rl0 + r];
              ft[(rl0 + r) * 132 + cl] = val;
            }
          }
        }
      }
      __syncthreads();
      #pragma unroll
      for (int i = 0; i < IT; ++i) {
        int idx = i * 256 + tid;
        int rrow = idx >> 5, c4 = (idx & 31) << 2;
        float4 v = *(const float4*)&ft[rrow * 132 + c4];
        size_t gidx = (size_t)(m0 + prow0 + rrow) * ldc + (n0 + c4);
        if (Res) {
          const float4 rv = *(const float4*)&Res[(size_t)bz * sRes + gidx];
          v.x += rv.x; v.y += rv.y; v.z += rv.z; v.w += rv.w;
        }
        *(float4*)&Cf[(size_t)bz * sC + gidx] = v;
      }
    }
  }
}

#define GEMM_ARGS const unsigned short* A, const unsigned short* Bm, void* Cm,            \
                  const float* biasRow, const float* biasCol, const float* Res,            \
                  int K, int lda, int ldb, int ldc, float scale,                           \
                  long long sA, long long sB, long long sC, long long sRes
#define GEMM_PASS A, Bm, Cm, biasRow, biasCol, Res, K, lda, ldb, ldc, scale, sA, sB, sC, sRes

__global__ __launch_bounds__(256) void gemm_qkv(GEMM_ARGS) { gemm_body<64, 0>(GEMM_PASS); }
__global__ __launch_bounds__(256) void gemm_s(GEMM_ARGS)   { gemm_body<64, 0>(GEMM_PASS); }
__global__ __launch_bounds__(256) void gemm_pv(GEMM_ARGS)  { gemm_body<64, 0>(GEMM_PASS); }
__global__ __launch_bounds__(256) void gemm_res(GEMM_ARGS) { gemm_body<32, 1>(GEMM_PASS); }

// ---------------- in-place row softmax on bf16 scores ----------------
__global__ void softmax_rows(unsigned short* __restrict__ S) {
  size_t roff = ((size_t)blockIdx.y * HWP + blockIdx.x) * HWP;
  unsigned short* row = S + roff;
  const int tid = threadIdx.x;
  float v[16];
  s16x8 rlo = *(const s16x8*)&row[tid * 16];
  s16x8 rhi = *(const s16x8*)&row[tid * 16 + 8];
  #pragma unroll
  for (int j = 0; j < 8; ++j) {
    v[j] = bf2f((unsigned short)rlo[j]);
    v[8 + j] = bf2f((unsigned short)rhi[j]);
  }
  float mx = v[0];
  #pragma unroll
  for (int j = 1; j < 16; ++j) mx = fmaxf(mx, v[j]);
  #pragma unroll
  for (int o = 32; o; o >>= 1) mx = fmaxf(mx, __shfl_xor(mx, o));
  __shared__ float red[8];
  const int wv = tid >> 6;
  if ((tid & 63) == 0) red[wv] = mx;
  __syncthreads();
  mx = fmaxf(fmaxf(red[0], red[1]), fmaxf(red[2], red[3]));
  float s = 0.f;
  #pragma unroll
  for (int j = 0; j < 16; ++j) { v[j] = __expf(v[j] - mx); s += v[j]; }
  #pragma unroll
  for (int o = 32; o; o >>= 1) s += __shfl_xor(s, o);
  if ((tid & 63) == 0) red[4 + wv] = s;
  __syncthreads();
  s = red[4] + red[5] + red[6] + red[7];
  float inv = 1.f / s;
  #pragma unroll
  for (int j = 0; j < 8; ++j) {
    rlo[j] = (short)f2bf(v[j] * inv);
    rhi[j] = (short)f2bf(v[8 + j] * inv);
  }
  *(s16x8*)&row[tid * 16] = rlo;
  *(s16x8*)&row[tid * 16 + 8] = rhi;
}

extern "C" void kernel_launch(void* const* d_in, const int* in_sizes, int n_in,
                              void* d_out, int out_size, void* d_ws, size_t ws_size,
                              hipStream_t stream) {
  (void)in_sizes; (void)n_in; (void)out_size;
  const float* x   = (const float*)d_in[0];
  const float* nsc = (const float*)d_in[1];
  const float* nbi = (const float*)d_in[2];
  const float* wq  = (const float*)d_in[3];
  const float* bq  = (const float*)d_in[4];
  const float* wk  = (const float*)d_in[5];
  const float* bk  = (const float*)d_in[6];
  const float* wv  = (const float*)d_in[7];
  const float* bv  = (const float*)d_in[8];
  const float* wp  = (const float*)d_in[9];
  const float* bp  = (const float*)d_in[10];
  float* out = (float*)d_out;
  char* ws = (char*)d_ws;

  const size_t nW = (size_t)CCH * CCH;
  unsigned short* wb = (unsigned short*)ws;            // 2 MB
  float* bcat = (float*)(ws + 4 * nW * 2);             // 6 KB
  float* stats = bcat + 1536;                          // 2 KB
  const size_t o_h = 4 * nW * 2 + 16384;
  unsigned short* ht  = (unsigned short*)(ws + o_h);   // 32 MB  (b, p, 512)
  unsigned short* qkv = ht + (size_t)BATCH * HWP * CCH;        // 96 MB (b, p, 1536)
  unsigned short* vT  = qkv + (size_t)BATCH * HWP * 1536;      // 32 MB (b, c, p)
  unsigned short* Sb  = vT + (size_t)BATCH * CCH * HWP;        // G*32 MB slice (reused)
  unsigned short* ot  = ht;                            // alias: ht dead after QKV gemm
  const size_t o_S = o_h + ((size_t)BATCH * HWP * (CCH + 1536 + CCH)) * 2;
  const size_t sS1b = (size_t)HWP * HWP * 2;           // score bytes per batch
  int G = 4;                                           // slice size: L3-resident S, adaptive
  while (G > 1 && o_S + (size_t)G * sS1b > ws_size) G >>= 1;

  const long long sHC  = (long long)HWP * CCH;         // 2M elements
  const long long sQKV = (long long)HWP * 1536;
  const long long sS1  = (long long)HWP * HWP;

  cvt_w<<<dim3((unsigned)((nW + 255) / 256)), dim3(256), 0, stream>>>(
      wq, wk, wv, wp, bq, bk, bv, wb, bcat);
  gn_stats<<<dim3(BATCH * NG), dim3(256), 0, stream>>>(x, stats);
  gn_apply<<<dim3(HWP / 64, CCH / 64, BATCH), dim3(256), 0, stream>>>(x, stats, nsc, nbi, ht);

  // fused QKV: qkv[p][o] = sum_c h_t[p][c] wqkv[o][c] + bcat[o]
  gemm_qkv<<<dim3(1536 / 128, HWP / 128, BATCH), dim3(256), 0, stream>>>(
      ht, wb, qkv, nullptr, bcat, nullptr,
      CCH, CCH, CCH, 1536, 1.f, sHC, 0, sQKV, 0);

  transpose_v<<<dim3(HWP / 64, CCH / 64, BATCH), dim3(256), 0, stream>>>(qkv, vT);

  const float sc = 0.04419417382415922f;               // 512^-0.5
  for (int b0 = 0; b0 < BATCH; b0 += G) {
    // S[d][e] = scale * sum_c q[d][c] k[e][c]   (G batches per slice, S stays L3-resident)
    gemm_s<<<dim3(HWP / 128, HWP / 128, G), dim3(256), 0, stream>>>(
        qkv + (size_t)b0 * sQKV, qkv + 512 + (size_t)b0 * sQKV, Sb,
        nullptr, nullptr, nullptr,
        CCH, 1536, 1536, HWP, sc, sQKV, sQKV, sS1, 0);
    softmax_rows<<<dim3(HWP, G), 256, 0, stream>>>(Sb);
    // o_t[d][c] = sum_e P[d][e] vT[c][e]
    gemm_pv<<<dim3(CCH / 128, HWP / 128, G), dim3(256), 0, stream>>>(
        Sb, vT + (size_t)b0 * sHC, ot + (size_t)b0 * sHC,
        nullptr, nullptr, nullptr,
        HWP, HWP, HWP, CCH, 1.f, sS1, sHC, sHC, 0);
  }

  // final: out[o][p] = x[o][p] + bp[o] + sum_c wp[o][c] o_t[p][c]   (f32, BK=32 high-occ)
  gemm_res<<<dim3(HWP / 128, CCH / 128, BATCH), dim3(256), 0, stream>>>(
      wb + 3 * nW, ot, out, bp, nullptr, x,
      CCH, CCH, CCH, HWP, 1.f, 0, sHC, sHC, sHC);
}

// Round 6
// 937.150 us; speedup vs baseline: 1.1601x; 1.1601x over previous
//
#include <hip/hip_runtime.h>

// AttnBlock2D: GroupNorm -> fused QKV 1x1conv -> 1-head attention (hw=4096, dh=512) -> proj + residual
// b=8, c=512, h=w=64. bf16 MFMA (16x16x32), f32 accumulate.
// R6: (1) gemm body back to m97 single-buffered 32KB LDS structure (2 barriers/K-step,
//     ~5 blocks/CU) — explicit dbuf at 64KB LDS was the m132 occupancy regression;
//     (2) MODE-1 f32 epilogue rewritten with COMPILE-TIME acc indexing (R5's runtime
//     index spilled acc to scratch: VGPR 56, 1GB scratch writes); (3) gemm_res=BK64 MODE1.

#define BATCH 8
#define CCH 512
#define HWP 4096
#define NG 32

typedef __attribute__((ext_vector_type(8))) short s16x8;
typedef __attribute__((ext_vector_type(4))) float f32x4;

__device__ __forceinline__ unsigned short f2bf(float f) {
  union { float f; unsigned u; } v; v.f = f;
  return (unsigned short)((v.u + 0x7FFFu + ((v.u >> 16) & 1u)) >> 16);
}
__device__ __forceinline__ float bf2f(unsigned short h) {
  union { unsigned u; float f; } v; v.u = ((unsigned)h) << 16;
  return v.f;
}

// ---------------- weight convert f32 -> bf16 (4 matrices) + qkv bias concat ----------------
__global__ void cvt_w(const float* __restrict__ w0, const float* __restrict__ w1,
                      const float* __restrict__ w2, const float* __restrict__ w3,
                      const float* __restrict__ bq, const float* __restrict__ bk,
                      const float* __restrict__ bv,
                      unsigned short* __restrict__ out, float* __restrict__ bcat) {
  int i = blockIdx.x * 256 + threadIdx.x;
  const int n = CCH * CCH;
  if (i < CCH) {
    bcat[i]           = bq[i];
    bcat[CCH + i]     = bk[i];
    bcat[2 * CCH + i] = bv[i];
  }
  if (i < n) {
    out[i]         = f2bf(w0[i]);
    out[n + i]     = f2bf(w1[i]);
    out[2 * n + i] = f2bf(w2[i]);
    out[3 * n + i] = f2bf(w3[i]);
  }
}

// ---------------- GroupNorm stats: one block per (b,g) ----------------
__global__ void gn_stats(const float* __restrict__ x, float* __restrict__ stats) {
  const int bg = blockIdx.x;                     // b*32+g ; group data contiguous 16*4096 f32
  const float* base = x + (size_t)bg * (16 * HWP);
  float s = 0.f, sq = 0.f;
  for (int i = threadIdx.x; i < 16 * HWP / 4; i += 256) {
    float4 v = ((const float4*)base)[i];
    s += v.x + v.y + v.z + v.w;
    sq += v.x * v.x + v.y * v.y + v.z * v.z + v.w * v.w;
  }
  #pragma unroll
  for (int o = 32; o; o >>= 1) { s += __shfl_xor(s, o); sq += __shfl_xor(sq, o); }
  __shared__ float ls[4], lq[4];
  const int wv = threadIdx.x >> 6;
  if ((threadIdx.x & 63) == 0) { ls[wv] = s; lq[wv] = sq; }
  __syncthreads();
  if (threadIdx.x == 0) {
    s = ls[0] + ls[1] + ls[2] + ls[3];
    sq = lq[0] + lq[1] + lq[2] + lq[3];
    const float inv_n = 1.f / (16.f * HWP);
    float mean = s * inv_n;
    float var = sq * inv_n - mean * mean;
    stats[2 * bg] = mean;
    stats[2 * bg + 1] = rsqrtf(var + 1e-5f);
  }
}

// ---------------- GroupNorm apply + transpose -> h_t (hw, c) bf16 ----------------
__global__ void gn_apply(const float* __restrict__ x, const float* __restrict__ stats,
                         const float* __restrict__ scale, const float* __restrict__ bias,
                         unsigned short* __restrict__ ht) {
  // grid (HWP/64, CCH/64, B), block 256
  const int p0 = blockIdx.x * 64, c0 = blockIdx.y * 64, b = blockIdx.z;
  const int tx = threadIdx.x & 63, ty = threadIdx.x >> 6;
  __shared__ unsigned short tile[64][65];
  #pragma unroll 4
  for (int j = 0; j < 16; ++j) {
    int cl = ty + j * 4;
    int c = c0 + cl;
    int g = c >> 4;
    float mean = stats[(b * NG + g) * 2];
    float rstd = stats[(b * NG + g) * 2 + 1];
    float v = x[((size_t)(b * CCH + c)) * HWP + p0 + tx];
    v = (v - mean) * rstd * scale[c] + bias[c];
    tile[cl][tx] = f2bf(v);
  }
  __syncthreads();
  #pragma unroll 4
  for (int j = 0; j < 16; ++j) {
    int pl = ty + j * 4;
    ht[((size_t)b * HWP + p0 + pl) * CCH + c0 + tx] = tile[tx][pl];
  }
}

// ---------------- V transpose: qkv (b, p, 1536)[cols 1024:1536) -> vT (b, c, p) ----------------
__global__ void transpose_v(const unsigned short* __restrict__ qkv,
                            unsigned short* __restrict__ vT) {
  const int p0 = blockIdx.x * 64, c0 = blockIdx.y * 64, b = blockIdx.z;
  const int tx = threadIdx.x & 63, ty = threadIdx.x >> 6;
  __shared__ unsigned short tile[64][65];
  #pragma unroll 4
  for (int j = 0; j < 16; ++j) {
    int pl = ty + j * 4;
    tile[pl][tx] = qkv[((size_t)b * HWP + p0 + pl) * 1536 + 1024 + c0 + tx];
  }
  __syncthreads();
  #pragma unroll 4
  for (int j = 0; j < 16; ++j) {
    int cl = ty + j * 4;
    vT[((size_t)b * CCH + c0 + cl) * HWP + p0 + tx] = tile[tx][cl];
  }
}

// ---------------- NT GEMM body: C[.,.] = scale * A[M,K] * B[N,K]^T (+biases, +residual) ----------------
// 128x128 tile, 4 waves, 16x16x32 MFMA, BK=64. SINGLE-buffered 32KB LDS (m97 structure:
// stage -> barrier -> compute -> barrier). Pre-swizzled global_load_lds staging +
// XOR-swizzled ds_read (both-sides). Bijective XCD swizzle.
// MODE 0: bf16 out. MODE 1: f32 out, coalesced 2-pass LDS-bounce epilogue (compile-time
// acc indexing only — runtime indexing spills acc to scratch, rule #20).
template<int MODE>
__device__ __forceinline__ void gemm_body(
    const unsigned short* __restrict__ A, const unsigned short* __restrict__ Bm,
    void* __restrict__ Cm, const float* __restrict__ biasRow,
    const float* __restrict__ biasCol, const float* __restrict__ Res,
    int K, int lda, int ldb, int ldc, float scale,
    long long sA, long long sB, long long sC, long long sRes) {
  // --- bijective XCD swizzle ---
  const int nbx = gridDim.x, nby = gridDim.y;
  const int nb = nbx * nby * gridDim.z;
  int lin = (blockIdx.z * nby + blockIdx.y) * nbx + blockIdx.x;
  int bx, by, bz;
  if ((nb & 7) == 0) {
    int logical = (lin & 7) * (nb >> 3) + (lin >> 3);
    bx = logical % nbx;
    int t = logical / nbx;
    by = t % nby;
    bz = t / nby;
  } else { bx = blockIdx.x; by = blockIdx.y; bz = blockIdx.z; }

  const unsigned short* Ab = A + (size_t)bz * sA;
  const unsigned short* Bb = Bm + (size_t)bz * sB;
  const int m0 = by * 128, n0 = bx * 128;

  // single-buffer LDS: A-tile + B-tile = 32KB; MODE1 unions a 64x132 f32 bounce (33.8KB)
  constexpr int LDS_BYTES = (MODE == 1) ? (64 * 132 * 4) : (2 * 128 * 64 * 2);
  __shared__ __align__(16) unsigned char smraw[LDS_BYTES];
  unsigned short* lA = (unsigned short*)smraw;        // [128*64]
  unsigned short* lB = lA + 128 * 64;                 // [128*64]

  const int tid = threadIdx.x, wave = tid >> 6, lane = tid & 63;
  const int wr = (wave >> 1) * 64, wc = (wave & 1) * 64;
  const int lr = lane & 15, lkc = lane >> 4;
  f32x4 acc[4][4] = {};

  const int chunkBase = wave * 64 + lane;             // 0..255
  int srow[4], sc8[4];
  #pragma unroll
  for (int it = 0; it < 4; ++it) {
    int chunk = it * 256 + chunkBase;
    srow[it] = chunk >> 3;
    sc8[it] = (((chunk & 7) ^ (srow[it] & 7)) * 8);
  }

  for (int kt = 0; kt < K; kt += 64) {
    #pragma unroll
    for (int it = 0; it < 4; ++it) {
      __builtin_amdgcn_global_load_lds(
          (const __attribute__((address_space(1))) unsigned int*)(Ab + (size_t)(m0 + srow[it]) * lda + kt + sc8[it]),
          (__attribute__((address_space(3))) unsigned int*)(lA + (size_t)(it * 256 + wave * 64) * 8),
          16, 0, 0);
      __builtin_amdgcn_global_load_lds(
          (const __attribute__((address_space(1))) unsigned int*)(Bb + (size_t)(n0 + srow[it]) * ldb + kt + sc8[it]),
          (__attribute__((address_space(3))) unsigned int*)(lB + (size_t)(it * 256 + wave * 64) * 8),
          16, 0, 0);
    }
    __syncthreads();                                  // drains vmcnt (compiler-enforced)
    #pragma unroll
    for (int kk = 0; kk < 64; kk += 32) {
      const int jbase = (kk >> 3) + lkc;
      s16x8 af[4], bfv[4];
      #pragma unroll
      for (int m = 0; m < 4; ++m) {
        int r = wr + m * 16 + lr;
        af[m] = *(const s16x8*)&lA[r * 64 + (((jbase ^ (r & 7))) << 3)];
      }
      #pragma unroll
      for (int n = 0; n < 4; ++n) {
        int r = wc + n * 16 + lr;
        bfv[n] = *(const s16x8*)&lB[r * 64 + (((jbase ^ (r & 7))) << 3)];
      }
      #pragma unroll
      for (int m = 0; m < 4; ++m)
        #pragma unroll
        for (int n = 0; n < 4; ++n)
          acc[m][n] = __builtin_amdgcn_mfma_f32_16x16x32_bf16(af[m], bfv[n], acc[m][n], 0, 0, 0);
    }
    __syncthreads();                                  // protect LDS for next stage
  }

  if (MODE == 0) {
    const int r0 = (lane >> 4) * 4, ccol = lane & 15;
    #pragma unroll
    for (int m = 0; m < 4; ++m) {
      const int gm = m0 + wr + m * 16 + r0;
      #pragma unroll
      for (int n = 0; n < 4; ++n) {
        const int gn = n0 + wc + n * 16 + ccol;
        float bc = biasCol ? biasCol[gn] : 0.f;
        #pragma unroll
        for (int r = 0; r < 4; ++r) {
          const int grow = gm + r;
          float val = acc[m][n][r] * scale + bc;
          if (biasRow) val += biasRow[grow];
          size_t idx = (size_t)grow * ldc + gn;
          ((unsigned short*)Cm)[(size_t)bz * sC + idx] = f2bf(val);
        }
      }
    }
  } else {
    // f32 out: 2 passes of 64 rows; acc indices are all compile-time constants.
    float* ft = (float*)smraw;                        // [64][132]
    float* Cf = (float*)Cm;
    #pragma unroll
    for (int p = 0; p < 2; ++p) {
      __syncthreads();
      if (wr == p * 64) {                             // wave-uniform guard
        #pragma unroll
        for (int m = 0; m < 4; ++m) {
          const int rl0 = m * 16 + (lane >> 4) * 4;   // 0..63 within pass
          #pragma unroll
          for (int n = 0; n < 4; ++n) {
            const int cl = wc + n * 16 + (lane & 15);
            float bc = biasCol ? biasCol[n0 + cl] : 0.f;
            #pragma unroll
            for (int r = 0; r < 4; ++r) {
              float val = acc[m][n][r] * scale + bc;
              if (biasRow) val += biasRow[m0 + p * 64 + rl0 + r];
              ft[(rl0 + r) * 132 + cl] = val;
            }
          }
        }
      }
      __syncthreads();
      #pragma unroll
      for (int i = 0; i < 8; ++i) {
        int idx = i * 256 + tid;
        int rrow = idx >> 5, c4 = (idx & 31) << 2;
        float4 v = *(const float4*)&ft[rrow * 132 + c4];
        size_t gidx = (size_t)(m0 + p * 64 + rrow) * ldc + (n0 + c4);
        if (Res) {
          const float4 rv = *(const float4*)&Res[(size_t)bz * sRes + gidx];
          v.x += rv.x; v.y += rv.y; v.z += rv.z; v.w += rv.w;
        }
        *(float4*)&Cf[(size_t)bz * sC + gidx] = v;
      }
    }
  }
}

#define GEMM_ARGS const unsigned short* A, const unsigned short* Bm, void* Cm,            \
                  const float* biasRow, const float* biasCol, const float* Res,            \
                  int K, int lda, int ldb, int ldc, float scale,                           \
                  long long sA, long long sB, long long sC, long long sRes
#define GEMM_PASS A, Bm, Cm, biasRow, biasCol, Res, K, lda, ldb, ldc, scale, sA, sB, sC, sRes

__global__ __launch_bounds__(256) void gemm_qkv(GEMM_ARGS) { gemm_body<0>(GEMM_PASS); }
__global__ __launch_bounds__(256) void gemm_s(GEMM_ARGS)   { gemm_body<0>(GEMM_PASS); }
__global__ __launch_bounds__(256) void gemm_pv(GEMM_ARGS)  { gemm_body<0>(GEMM_PASS); }
__global__ __launch_bounds__(256) void gemm_res(GEMM_ARGS) { gemm_body<1>(GEMM_PASS); }

// ---------------- in-place row softmax on bf16 scores ----------------
__global__ void softmax_rows(unsigned short* __restrict__ S) {
  size_t roff = ((size_t)blockIdx.y * HWP + blockIdx.x) * HWP;
  unsigned short* row = S + roff;
  const int tid = threadIdx.x;
  float v[16];
  s16x8 rlo = *(const s16x8*)&row[tid * 16];
  s16x8 rhi = *(const s16x8*)&row[tid * 16 + 8];
  #pragma unroll
  for (int j = 0; j < 8; ++j) {
    v[j] = bf2f((unsigned short)rlo[j]);
    v[8 + j] = bf2f((unsigned short)rhi[j]);
  }
  float mx = v[0];
  #pragma unroll
  for (int j = 1; j < 16; ++j) mx = fmaxf(mx, v[j]);
  #pragma unroll
  for (int o = 32; o; o >>= 1) mx = fmaxf(mx, __shfl_xor(mx, o));
  __shared__ float red[8];
  const int wv = tid >> 6;
  if ((tid & 63) == 0) red[wv] = mx;
  __syncthreads();
  mx = fmaxf(fmaxf(red[0], red[1]), fmaxf(red[2], red[3]));
  float s = 0.f;
  #pragma unroll
  for (int j = 0; j < 16; ++j) { v[j] = __expf(v[j] - mx); s += v[j]; }
  #pragma unroll
  for (int o = 32; o; o >>= 1) s += __shfl_xor(s, o);
  if ((tid & 63) == 0) red[4 + wv] = s;
  __syncthreads();
  s = red[4] + red[5] + red[6] + red[7];
  float inv = 1.f / s;
  #pragma unroll
  for (int j = 0; j < 8; ++j) {
    rlo[j] = (short)f2bf(v[j] * inv);
    rhi[j] = (short)f2bf(v[8 + j] * inv);
  }
  *(s16x8*)&row[tid * 16] = rlo;
  *(s16x8*)&row[tid * 16 + 8] = rhi;
}

extern "C" void kernel_launch(void* const* d_in, const int* in_sizes, int n_in,
                              void* d_out, int out_size, void* d_ws, size_t ws_size,
                              hipStream_t stream) {
  (void)in_sizes; (void)n_in; (void)out_size;
  const float* x   = (const float*)d_in[0];
  const float* nsc = (const float*)d_in[1];
  const float* nbi = (const float*)d_in[2];
  const float* wq  = (const float*)d_in[3];
  const float* bq  = (const float*)d_in[4];
  const float* wk  = (const float*)d_in[5];
  const float* bk  = (const float*)d_in[6];
  const float* wv  = (const float*)d_in[7];
  const float* bv  = (const float*)d_in[8];
  const float* wp  = (const float*)d_in[9];
  const float* bp  = (const float*)d_in[10];
  float* out = (float*)d_out;
  char* ws = (char*)d_ws;

  const size_t nW = (size_t)CCH * CCH;
  unsigned short* wb = (unsigned short*)ws;            // 2 MB
  float* bcat = (float*)(ws + 4 * nW * 2);             // 6 KB
  float* stats = bcat + 1536;                          // 2 KB
  const size_t o_h = 4 * nW * 2 + 16384;
  unsigned short* ht  = (unsigned short*)(ws + o_h);   // 32 MB  (b, p, 512)
  unsigned short* qkv = ht + (size_t)BATCH * HWP * CCH;        // 96 MB (b, p, 1536)
  unsigned short* vT  = qkv + (size_t)BATCH * HWP * 1536;      // 32 MB (b, c, p)
  unsigned short* Sb  = vT + (size_t)BATCH * CCH * HWP;        // G*32 MB slice (reused)
  unsigned short* ot  = ht;                            // alias: ht dead after QKV gemm
  const size_t o_S = o_h + ((size_t)BATCH * HWP * (CCH + 1536 + CCH)) * 2;
  const size_t sS1b = (size_t)HWP * HWP * 2;           // score bytes per batch
  int G = 4;                                           // slice size: L3-resident S, adaptive
  while (G > 1 && o_S + (size_t)G * sS1b > ws_size) G >>= 1;

  const long long sHC  = (long long)HWP * CCH;         // 2M elements
  const long long sQKV = (long long)HWP * 1536;
  const long long sS1  = (long long)HWP * HWP;

  cvt_w<<<dim3((unsigned)((nW + 255) / 256)), dim3(256), 0, stream>>>(
      wq, wk, wv, wp, bq, bk, bv, wb, bcat);
  gn_stats<<<dim3(BATCH * NG), dim3(256), 0, stream>>>(x, stats);
  gn_apply<<<dim3(HWP / 64, CCH / 64, BATCH), dim3(256), 0, stream>>>(x, stats, nsc, nbi, ht);

  // fused QKV: qkv[p][o] = sum_c h_t[p][c] wqkv[o][c] + bcat[o]
  gemm_qkv<<<dim3(1536 / 128, HWP / 128, BATCH), dim3(256), 0, stream>>>(
      ht, wb, qkv, nullptr, bcat, nullptr,
      CCH, CCH, CCH, 1536, 1.f, sHC, 0, sQKV, 0);

  transpose_v<<<dim3(HWP / 64, CCH / 64, BATCH), dim3(256), 0, stream>>>(qkv, vT);

  const float sc = 0.04419417382415922f;               // 512^-0.5
  for (int b0 = 0; b0 < BATCH; b0 += G) {
    // S[d][e] = scale * sum_c q[d][c] k[e][c]   (G batches per slice, S stays L3-resident)
    gemm_s<<<dim3(HWP / 128, HWP / 128, G), dim3(256), 0, stream>>>(
        qkv + (size_t)b0 * sQKV, qkv + 512 + (size_t)b0 * sQKV, Sb,
        nullptr, nullptr, nullptr,
        CCH, 1536, 1536, HWP, sc, sQKV, sQKV, sS1, 0);
    softmax_rows<<<dim3(HWP, G), 256, 0, stream>>>(Sb);
    // o_t[d][c] = sum_e P[d][e] vT[c][e]
    gemm_pv<<<dim3(CCH / 128, HWP / 128, G), dim3(256), 0, stream>>>(
        Sb, vT + (size_t)b0 * sHC, ot + (size_t)b0 * sHC,
        nullptr, nullptr, nullptr,
        HWP, HWP, HWP, CCH, 1.f, sS1, sHC, sHC, 0);
  }

  // final: out[o][p] = x[o][p] + bp[o] + sum_c wp[o][c] o_t[p][c]   (f32, 2-pass bounce)
  gemm_res<<<dim3(HWP / 128, CCH / 128, BATCH), dim3(256), 0, stream>>>(
      wb + 3 * nW, ot, out, bp, nullptr, x,
      CCH, CCH, CCH, HWP, 1.f, 0, sHC, sHC, sHC);
}

// Round 7
// 877.919 us; speedup vs baseline: 1.2384x; 1.0675x over previous
//
#include <hip/hip_runtime.h>

// AttnBlock2D: GroupNorm -> fused QKV -> 1-head attention (hw=4096, dh=512) -> proj + residual
// R7: S/PV/QKV on a 256x256-tile 8-wave deep-pipelined engine (counted vmcnt, raw s_barrier,
//     stage t+2 while t+1 in flight -> staging latency hidden under 128 MFMA/K-tile).
//     gemm_res reverts to the R3 double-buffered 128x128 engine (best measured: 101us).

#define BATCH 8
#define CCH 512
#define HWP 4096
#define NG 32

#define AS1 __attribute__((address_space(1)))
#define AS3 __attribute__((address_space(3)))

typedef __attribute__((ext_vector_type(8))) short s16x8;
typedef __attribute__((ext_vector_type(4))) float f32x4;

__device__ __forceinline__ unsigned short f2bf(float f) {
  union { float f; unsigned u; } v; v.f = f;
  return (unsigned short)((v.u + 0x7FFFu + ((v.u >> 16) & 1u)) >> 16);
}
__device__ __forceinline__ float bf2f(unsigned short h) {
  union { unsigned u; float f; } v; v.u = ((unsigned)h) << 16;
  return v.f;
}

// ---------------- weight convert f32 -> bf16 (4 matrices) + qkv bias concat ----------------
__global__ void cvt_w(const float* __restrict__ w0, const float* __restrict__ w1,
                      const float* __restrict__ w2, const float* __restrict__ w3,
                      const float* __restrict__ bq, const float* __restrict__ bk,
                      const float* __restrict__ bv,
                      unsigned short* __restrict__ out, float* __restrict__ bcat) {
  int i = blockIdx.x * 256 + threadIdx.x;
  const int n = CCH * CCH;
  if (i < CCH) {
    bcat[i]           = bq[i];
    bcat[CCH + i]     = bk[i];
    bcat[2 * CCH + i] = bv[i];
  }
  if (i < n) {
    out[i]         = f2bf(w0[i]);
    out[n + i]     = f2bf(w1[i]);
    out[2 * n + i] = f2bf(w2[i]);
    out[3 * n + i] = f2bf(w3[i]);
  }
}

// ---------------- GroupNorm stats ----------------
__global__ void gn_stats(const float* __restrict__ x, float* __restrict__ stats) {
  const int bg = blockIdx.x;
  const float* base = x + (size_t)bg * (16 * HWP);
  float s = 0.f, sq = 0.f;
  for (int i = threadIdx.x; i < 16 * HWP / 4; i += 256) {
    float4 v = ((const float4*)base)[i];
    s += v.x + v.y + v.z + v.w;
    sq += v.x * v.x + v.y * v.y + v.z * v.z + v.w * v.w;
  }
  #pragma unroll
  for (int o = 32; o; o >>= 1) { s += __shfl_xor(s, o); sq += __shfl_xor(sq, o); }
  __shared__ float ls[4], lq[4];
  const int wv = threadIdx.x >> 6;
  if ((threadIdx.x & 63) == 0) { ls[wv] = s; lq[wv] = sq; }
  __syncthreads();
  if (threadIdx.x == 0) {
    s = ls[0] + ls[1] + ls[2] + ls[3];
    sq = lq[0] + lq[1] + lq[2] + lq[3];
    const float inv_n = 1.f / (16.f * HWP);
    float mean = s * inv_n;
    float var = sq * inv_n - mean * mean;
    stats[2 * bg] = mean;
    stats[2 * bg + 1] = rsqrtf(var + 1e-5f);
  }
}

// ---------------- GroupNorm apply + transpose -> h_t (hw, c) bf16 ----------------
__global__ void gn_apply(const float* __restrict__ x, const float* __restrict__ stats,
                         const float* __restrict__ scale, const float* __restrict__ bias,
                         unsigned short* __restrict__ ht) {
  const int p0 = blockIdx.x * 64, c0 = blockIdx.y * 64, b = blockIdx.z;
  const int tx = threadIdx.x & 63, ty = threadIdx.x >> 6;
  __shared__ unsigned short tile[64][65];
  #pragma unroll 4
  for (int j = 0; j < 16; ++j) {
    int cl = ty + j * 4;
    int c = c0 + cl;
    int g = c >> 4;
    float mean = stats[(b * NG + g) * 2];
    float rstd = stats[(b * NG + g) * 2 + 1];
    float v = x[((size_t)(b * CCH + c)) * HWP + p0 + tx];
    v = (v - mean) * rstd * scale[c] + bias[c];
    tile[cl][tx] = f2bf(v);
  }
  __syncthreads();
  #pragma unroll 4
  for (int j = 0; j < 16; ++j) {
    int pl = ty + j * 4;
    ht[((size_t)b * HWP + p0 + pl) * CCH + c0 + tx] = tile[tx][pl];
  }
}

// ---------------- V transpose: qkv[:,1024:1536) -> vT (b, c, p) ----------------
__global__ void transpose_v(const unsigned short* __restrict__ qkv,
                            unsigned short* __restrict__ vT) {
  const int p0 = blockIdx.x * 64, c0 = blockIdx.y * 64, b = blockIdx.z;
  const int tx = threadIdx.x & 63, ty = threadIdx.x >> 6;
  __shared__ unsigned short tile[64][65];
  #pragma unroll 4
  for (int j = 0; j < 16; ++j) {
    int pl = ty + j * 4;
    tile[pl][tx] = qkv[((size_t)b * HWP + p0 + pl) * 1536 + 1024 + c0 + tx];
  }
  __syncthreads();
  #pragma unroll 4
  for (int j = 0; j < 16; ++j) {
    int cl = ty + j * 4;
    vT[((size_t)b * CCH + c0 + cl) * HWP + p0 + tx] = tile[tx][cl];
  }
}

// ================= 256x256-tile deep-pipelined NT GEMM (bf16 out) =================
// 8 waves (2M x 4N), 512 threads, BK=64, per-wave output 128 x (16*N_REP).
// 2 LDS buffers; stage K-tile t+2 after tile t's reads complete; counted vmcnt
// (never 0 mid-loop) retires tile t+1 which had a full K-tile of compute to land.
template<int N_REP>
__device__ __forceinline__ void wait_vm_lpt() {
  if constexpr (N_REP == 4) asm volatile("s_waitcnt vmcnt(8)" ::: "memory");
  else                      asm volatile("s_waitcnt vmcnt(6)" ::: "memory");
}

template<int N_REP>
__device__ __forceinline__ void gemm256_body(
    const unsigned short* __restrict__ A, const unsigned short* __restrict__ Bm,
    unsigned short* __restrict__ C, const float* __restrict__ biasCol,
    int K, int lda, int ldb, int ldc, float scale,
    long long sA, long long sB, long long sC) {
  constexpr int BN = 64 * N_REP;
  constexpr int NB_IT = BN / 64;           // B-stage loads per thread
  // --- bijective XCD swizzle ---
  const int nbx = gridDim.x, nby = gridDim.y;
  const int nb = nbx * nby * gridDim.z;
  int lin = (blockIdx.z * nby + blockIdx.y) * nbx + blockIdx.x;
  int bx, by, bz;
  if ((nb & 7) == 0) {
    int logical = (lin & 7) * (nb >> 3) + (lin >> 3);
    bx = logical % nbx;
    int t = logical / nbx;
    by = t % nby;
    bz = t / nby;
  } else { bx = blockIdx.x; by = blockIdx.y; bz = blockIdx.z; }

  const unsigned short* __restrict__ Ab = A + (size_t)bz * sA;
  const unsigned short* __restrict__ Bb = Bm + (size_t)bz * sB;
  unsigned short* __restrict__ Cb = C + (size_t)bz * sC;
  const int m0 = by * 256, n0 = bx * BN;

  __shared__ __align__(16) unsigned short lsA[2][256 * 64];
  __shared__ __align__(16) unsigned short lsB[2][BN * 64];

  const int tid = threadIdx.x, wave = tid >> 6, lane = tid & 63;
  const int wr = (wave >> 2) * 128;                 // wave M-offset
  const int wc = (wave & 3) * (16 * N_REP);         // wave N-offset
  const int lr = lane & 15, lkc = lane >> 4;

  int aRow[4], aCol[4];
  #pragma unroll
  for (int it = 0; it < 4; ++it) {
    int c = it * 512 + tid;
    int row = c >> 3;
    aRow[it] = row;
    aCol[it] = ((c & 7) ^ (row & 7)) * 8;
  }
  int bRow[NB_IT], bCol[NB_IT];
  #pragma unroll
  for (int it = 0; it < NB_IT; ++it) {
    int c = it * 512 + tid;
    int row = c >> 3;
    bRow[it] = row;
    bCol[it] = ((c & 7) ^ (row & 7)) * 8;
  }

  #define STAGE256(buf, kt)                                                                  \
    { _Pragma("unroll")                                                                      \
      for (int it = 0; it < 4; ++it)                                                         \
        __builtin_amdgcn_global_load_lds(                                                    \
            (const AS1 unsigned int*)(Ab + (size_t)(m0 + aRow[it]) * lda + (kt) + aCol[it]), \
            (AS3 unsigned int*)(&lsA[buf][0] + (size_t)(it * 512 + tid) * 8), 16, 0, 0);     \
      _Pragma("unroll")                                                                      \
      for (int it = 0; it < NB_IT; ++it)                                                     \
        __builtin_amdgcn_global_load_lds(                                                    \
            (const AS1 unsigned int*)(Bb + (size_t)(n0 + bRow[it]) * ldb + (kt) + bCol[it]), \
            (AS3 unsigned int*)(&lsB[buf][0] + (size_t)(it * 512 + tid) * 8), 16, 0, 0);     \
    }

  const int nkt = K >> 6;
  f32x4 acc[8][N_REP] = {};

  STAGE256(0, 0);
  STAGE256(1, 64);
  wait_vm_lpt<N_REP>();                             // tile 0 landed; tile 1 in flight
  __builtin_amdgcn_sched_barrier(0);
  __builtin_amdgcn_s_barrier();
  __builtin_amdgcn_sched_barrier(0);

  for (int t = 0; t < nkt; ++t) {
    const int cur = t & 1;
    const unsigned short* __restrict__ pA = &lsA[cur][0];
    const unsigned short* __restrict__ pB = &lsB[cur][0];
    #pragma unroll
    for (int kk = 0; kk < 64; kk += 32) {
      const int jb = (kk >> 3) + lkc;
      s16x8 af[8];
      #pragma unroll
      for (int m = 0; m < 8; ++m) {
        int r = wr + m * 16 + lr;
        af[m] = *(const s16x8*)&pA[r * 64 + ((jb ^ (r & 7)) << 3)];
      }
      #pragma unroll
      for (int n = 0; n < N_REP; ++n) {
        int rb = wc + n * 16 + lr;
        s16x8 bfv = *(const s16x8*)&pB[rb * 64 + ((jb ^ (rb & 7)) << 3)];
        #pragma unroll
        for (int m = 0; m < 8; ++m)
          acc[m][n] = __builtin_amdgcn_mfma_f32_16x16x32_bf16(af[m], bfv, acc[m][n], 0, 0, 0);
      }
    }
    if (t == nkt - 1) break;
    __builtin_amdgcn_sched_barrier(0);
    __builtin_amdgcn_s_barrier();                   // all reads of buf cur done
    __builtin_amdgcn_sched_barrier(0);
    if (t + 2 < nkt) {
      STAGE256(cur, (t + 2) * 64);                  // overwrite cur with tile t+2
      wait_vm_lpt<N_REP>();                         // retires tile t+1 (never 0)
    } else {
      asm volatile("s_waitcnt vmcnt(0)" ::: "memory");
    }
    __builtin_amdgcn_sched_barrier(0);
    __builtin_amdgcn_s_barrier();                   // tile t+1 visible to all waves
    __builtin_amdgcn_sched_barrier(0);
  }
  #undef STAGE256

  const int r0 = (lane >> 4) * 4, ccol = lane & 15;
  #pragma unroll
  for (int m = 0; m < 8; ++m) {
    const int gm = m0 + wr + m * 16 + r0;
    #pragma unroll
    for (int n = 0; n < N_REP; ++n) {
      const int gn = n0 + wc + n * 16 + ccol;
      const float bc = biasCol ? biasCol[gn] : 0.f;
      #pragma unroll
      for (int r = 0; r < 4; ++r) {
        float v = acc[m][n][r] * scale + bc;
        Cb[(size_t)(gm + r) * ldc + gn] = f2bf(v);
      }
    }
  }
}

#define G256_ARGS const unsigned short* A, const unsigned short* Bm, unsigned short* C,   \
                  const float* biasCol, int K, int lda, int ldb, int ldc, float scale,    \
                  long long sA, long long sB, long long sC
#define G256_PASS A, Bm, C, biasCol, K, lda, ldb, ldc, scale, sA, sB, sC

__global__ __launch_bounds__(512, 2) void gemm_qkv(G256_ARGS) { gemm256_body<4>(G256_PASS); }
__global__ __launch_bounds__(512, 2) void gemm_s(G256_ARGS)   { gemm256_body<4>(G256_PASS); }
__global__ __launch_bounds__(512, 2) void gemm_pv(G256_ARGS)  { gemm256_body<2>(G256_PASS); }

// ================= R3 double-buffered 128x128 engine, f32-out + residual (gemm_res) =================
__global__ __launch_bounds__(256)
void gemm_res(const unsigned short* __restrict__ A, const unsigned short* __restrict__ Bm,
              float* __restrict__ Cm, const float* __restrict__ biasRow,
              const float* __restrict__ Res,
              int K, int lda, int ldb, int ldc,
              long long sC, long long sRes) {
  const int nbx = gridDim.x, nby = gridDim.y;
  const int nb = nbx * nby * gridDim.z;
  int lin = (blockIdx.z * nby + blockIdx.y) * nbx + blockIdx.x;
  int bx, by, bz;
  if ((nb & 7) == 0) {
    int logical = (lin & 7) * (nb >> 3) + (lin >> 3);
    bx = logical % nbx;
    int t = logical / nbx;
    by = t % nby;
    bz = t / nby;
  } else { bx = blockIdx.x; by = blockIdx.y; bz = blockIdx.z; }

  const unsigned short* Ab = A;                     // weights: no batch stride
  const unsigned short* Bb = Bm + (size_t)bz * ((size_t)HWP * CCH);
  const int m0 = by * 128, n0 = bx * 128;
  __shared__ __align__(16) unsigned short sm[2][2][128 * 64];
  const int tid = threadIdx.x, wave = tid >> 6, lane = tid & 63;
  const int wr = (wave >> 1) * 64, wc = (wave & 1) * 64;
  const int lr = lane & 15, lkc = lane >> 4;
  f32x4 acc[4][4] = {};

  const int chunkBase = wave * 64 + lane;
  int srow[4], sc8[4];
  #pragma unroll
  for (int it = 0; it < 4; ++it) {
    int chunk = it * 256 + chunkBase;
    srow[it] = chunk >> 3;
    sc8[it] = (((chunk & 7) ^ (srow[it] & 7)) * 8);
  }

  #define STAGE(buf, kt)                                                                 \
    { _Pragma("unroll")                                                                  \
      for (int it = 0; it < 4; ++it) {                                                   \
        __builtin_amdgcn_global_load_lds(                                                \
            (const AS1 unsigned int*)(Ab + (size_t)(m0 + srow[it]) * lda + (kt) + sc8[it]), \
            (AS3 unsigned int*)(&sm[0][buf][0] + (size_t)(it * 256 + wave * 64) * 8), 16, 0, 0); \
        __builtin_amdgcn_global_load_lds(                                                \
            (const AS1 unsigned int*)(Bb + (size_t)(n0 + srow[it]) * ldb + (kt) + sc8[it]), \
            (AS3 unsigned int*)(&sm[1][buf][0] + (size_t)(it * 256 + wave * 64) * 8), 16, 0, 0); \
      }                                                                                  \
    }

  STAGE(0, 0);
  __syncthreads();
  int cur = 0;
  for (int kt = 0; kt < K; kt += 64) {
    if (kt + 64 < K) STAGE(cur ^ 1, kt + 64);
    #pragma unroll
    for (int kk = 0; kk < 64; kk += 32) {
      const int jbase = (kk >> 3) + lkc;
      s16x8 af[4], bfv[4];
      #pragma unroll
      for (int m = 0; m < 4; ++m) {
        int r = wr + m * 16 + lr;
        af[m] = *(const s16x8*)&sm[0][cur][r * 64 + ((jbase ^ (r & 7)) << 3)];
      }
      #pragma unroll
      for (int n = 0; n < 4; ++n) {
        int r = wc + n * 16 + lr;
        bfv[n] = *(const s16x8*)&sm[1][cur][r * 64 + ((jbase ^ (r & 7)) << 3)];
      }
      #pragma unroll
      for (int m = 0; m < 4; ++m)
        #pragma unroll
        for (int n = 0; n < 4; ++n)
          acc[m][n] = __builtin_amdgcn_mfma_f32_16x16x32_bf16(af[m], bfv[n], acc[m][n], 0, 0, 0);
    }
    __syncthreads();
    cur ^= 1;
  }
  #undef STAGE

  // coalesced f32 epilogue via LDS bounce: 2 passes of 64 rows
  float* ft = (float*)&sm[0][0][0];
  #pragma unroll
  for (int pass = 0; pass < 2; ++pass) {
    __syncthreads();
    if ((wave >> 1) == pass) {
      #pragma unroll
      for (int m = 0; m < 4; ++m) {
        const int rl0 = m * 16 + (lane >> 4) * 4;
        #pragma unroll
        for (int n = 0; n < 4; ++n) {
          const int cl = wc + n * 16 + (lane & 15);
          #pragma unroll
          for (int r = 0; r < 4; ++r) {
            float val = acc[m][n][r];
            if (biasRow) val += biasRow[m0 + pass * 64 + rl0 + r];
            ft[(rl0 + r) * 132 + cl] = val;
          }
        }
      }
    }
    __syncthreads();
    #pragma unroll
    for (int i = 0; i < 8; ++i) {
      int idx = i * 256 + tid;
      int rrow = idx >> 5, c4 = (idx & 31) << 2;
      float4 v = *(const float4*)&ft[rrow * 132 + c4];
      size_t gidx = (size_t)(m0 + pass * 64 + rrow) * ldc + (n0 + c4);
      const float4 rv = *(const float4*)&Res[(size_t)bz * sRes + gidx];
      v.x += rv.x; v.y += rv.y; v.z += rv.z; v.w += rv.w;
      *(float4*)&Cm[(size_t)bz * sC + gidx] = v;
    }
  }
}

// ---------------- in-place row softmax on bf16 scores ----------------
__global__ void softmax_rows(unsigned short* __restrict__ S) {
  size_t roff = ((size_t)blockIdx.y * HWP + blockIdx.x) * HWP;
  unsigned short* row = S + roff;
  const int tid = threadIdx.x;
  float v[16];
  s16x8 rlo = *(const s16x8*)&row[tid * 16];
  s16x8 rhi = *(const s16x8*)&row[tid * 16 + 8];
  #pragma unroll
  for (int j = 0; j < 8; ++j) {
    v[j] = bf2f((unsigned short)rlo[j]);
    v[8 + j] = bf2f((unsigned short)rhi[j]);
  }
  float mx = v[0];
  #pragma unroll
  for (int j = 1; j < 16; ++j) mx = fmaxf(mx, v[j]);
  #pragma unroll
  for (int o = 32; o; o >>= 1) mx = fmaxf(mx, __shfl_xor(mx, o));
  __shared__ float red[8];
  const int wv = tid >> 6;
  if ((tid & 63) == 0) red[wv] = mx;
  __syncthreads();
  mx = fmaxf(fmaxf(red[0], red[1]), fmaxf(red[2], red[3]));
  float s = 0.f;
  #pragma unroll
  for (int j = 0; j < 16; ++j) { v[j] = __expf(v[j] - mx); s += v[j]; }
  #pragma unroll
  for (int o = 32; o; o >>= 1) s += __shfl_xor(s, o);
  if ((tid & 63) == 0) red[4 + wv] = s;
  __syncthreads();
  s = red[4] + red[5] + red[6] + red[7];
  float inv = 1.f / s;
  #pragma unroll
  for (int j = 0; j < 8; ++j) {
    rlo[j] = (short)f2bf(v[j] * inv);
    rhi[j] = (short)f2bf(v[8 + j] * inv);
  }
  *(s16x8*)&row[tid * 16] = rlo;
  *(s16x8*)&row[tid * 16 + 8] = rhi;
}

extern "C" void kernel_launch(void* const* d_in, const int* in_sizes, int n_in,
                              void* d_out, int out_size, void* d_ws, size_t ws_size,
                              hipStream_t stream) {
  (void)in_sizes; (void)n_in; (void)out_size;
  const float* x   = (const float*)d_in[0];
  const float* nsc = (const float*)d_in[1];
  const float* nbi = (const float*)d_in[2];
  const float* wq  = (const float*)d_in[3];
  const float* bq  = (const float*)d_in[4];
  const float* wk  = (const float*)d_in[5];
  const float* bk  = (const float*)d_in[6];
  const float* wv  = (const float*)d_in[7];
  const float* bv  = (const float*)d_in[8];
  const float* wp  = (const float*)d_in[9];
  const float* bp  = (const float*)d_in[10];
  float* out = (float*)d_out;
  char* ws = (char*)d_ws;

  const size_t nW = (size_t)CCH * CCH;
  unsigned short* wb = (unsigned short*)ws;            // 2 MB
  float* bcat = (float*)(ws + 4 * nW * 2);             // 6 KB
  float* stats = bcat + 1536;                          // 2 KB
  const size_t o_h = 4 * nW * 2 + 16384;
  unsigned short* ht  = (unsigned short*)(ws + o_h);   // 32 MB  (b, p, 512)
  unsigned short* qkv = ht + (size_t)BATCH * HWP * CCH;        // 96 MB (b, p, 1536)
  unsigned short* vT  = qkv + (size_t)BATCH * HWP * 1536;      // 32 MB (b, c, p)
  unsigned short* Sb  = vT + (size_t)BATCH * CCH * HWP;        // G*32 MB slice (reused)
  unsigned short* ot  = ht;                            // alias: ht dead after QKV gemm
  const size_t o_S = o_h + ((size_t)BATCH * HWP * (CCH + 1536 + CCH)) * 2;
  const size_t sS1b = (size_t)HWP * HWP * 2;
  int G = 4;
  while (G > 1 && o_S + (size_t)G * sS1b > ws_size) G >>= 1;

  const long long sHC  = (long long)HWP * CCH;
  const long long sQKV = (long long)HWP * 1536;
  const long long sS1  = (long long)HWP * HWP;

  cvt_w<<<dim3((unsigned)((nW + 255) / 256)), dim3(256), 0, stream>>>(
      wq, wk, wv, wp, bq, bk, bv, wb, bcat);
  gn_stats<<<dim3(BATCH * NG), dim3(256), 0, stream>>>(x, stats);
  gn_apply<<<dim3(HWP / 64, CCH / 64, BATCH), dim3(256), 0, stream>>>(x, stats, nsc, nbi, ht);

  // fused QKV: qkv[p][o] = sum_c h_t[p][c] wqkv[o][c] + bcat[o]   (256-tile engine)
  gemm_qkv<<<dim3(1536 / 256, HWP / 256, BATCH), dim3(512), 0, stream>>>(
      ht, wb, qkv, bcat, CCH, CCH, CCH, 1536, 1.f, sHC, 0, sQKV);

  transpose_v<<<dim3(HWP / 64, CCH / 64, BATCH), dim3(256), 0, stream>>>(qkv, vT);

  const float sc = 0.04419417382415922f;               // 512^-0.5
  for (int b0 = 0; b0 < BATCH; b0 += G) {
    // S[d][e] = sc * sum_c q[d][c] k[e][c]
    gemm_s<<<dim3(HWP / 256, HWP / 256, G), dim3(512), 0, stream>>>(
        qkv + (size_t)b0 * sQKV, qkv + 512 + (size_t)b0 * sQKV, Sb, nullptr,
        CCH, 1536, 1536, HWP, sc, sQKV, sQKV, sS1);
    softmax_rows<<<dim3(HWP, G), 256, 0, stream>>>(Sb);
    // o_t[d][c] = sum_e P[d][e] vT[c][e]   (BN=128 -> full grid at G=4)
    gemm_pv<<<dim3(CCH / 128, HWP / 256, G), dim3(512), 0, stream>>>(
        Sb, vT + (size_t)b0 * sHC, ot + (size_t)b0 * sHC, nullptr,
        HWP, HWP, HWP, CCH, 1.f, sS1, sHC, sHC);
  }

  // final: out[o][p] = x[o][p] + bp[o] + sum_c wp[o][c] o_t[p][c]   (R3 dbuf engine, f32)
  gemm_res<<<dim3(HWP / 128, CCH / 128, BATCH), dim3(256), 0, stream>>>(
      wb + 3 * nW, ot, out, bp, x, CCH, CCH, CCH, HWP, sHC, sHC);
}